// Round 1
// baseline (700.892 us; speedup 1.0000x reference)
//
#include <hip/hip_runtime.h>

// CascadeHierarchicalEmbedding: 3-level gated embedding cascade.
// ids: [B,H] int32 x3; emb tables f32 [V,64]; two gate MLPs 128->32->1.
// out: f32 [B,H,64].  N = B*H = 819200 tokens.

#define GDIM 64

// Transpose the two gate w1 matrices [128,32] -> [32,128] into workspace so
// that each output-neuron's weight row is contiguous (enables s_load_dwordx16
// wave-uniform scalar loads in the main kernel).
__global__ __launch_bounds__(256) void prep_transpose(
    const float* __restrict__ g0w1, const float* __restrict__ g1w1,
    float* __restrict__ wst) {
  int t = blockIdx.x * 256 + threadIdx.x;
  if (t < 4096) {
    int o = t >> 7, i = t & 127;
    wst[t] = g0w1[i * 32 + o];              // wst[0][o][i]
  } else if (t < 8192) {
    int u = t - 4096;
    int o = u >> 7, i = u & 127;
    wst[t] = g1w1[i * 32 + o];              // wst[1][o][i]
  }
}

// Evaluate one gate MLP: h = relu(x @ w1 + b1); g = sigmoid(h @ w2 + b2),
// where x = concat(fine, cur).  w1t is transposed [32][128]; all weight
// accesses are wave-uniform -> scalar loads (SGPR operand in v_fma).
__device__ __forceinline__ float gate_eval(
    const float (&fine)[GDIM], const float (&cur)[GDIM],
    const float* __restrict__ w1t, const float* __restrict__ b1,
    const float* __restrict__ w2, const float* __restrict__ b2) {
  float z = b2[0];
  for (int o = 0; o < 32; ++o) {
    const float* __restrict__ wr = w1t + (o << 7);
    float p0 = 0.f, p1 = 0.f, p2 = 0.f, p3 = 0.f;
#pragma unroll
    for (int i = 0; i < GDIM; i += 4) {
      p0 = fmaf(fine[i + 0], wr[i + 0], p0);
      p1 = fmaf(fine[i + 1], wr[i + 1], p1);
      p2 = fmaf(fine[i + 2], wr[i + 2], p2);
      p3 = fmaf(fine[i + 3], wr[i + 3], p3);
    }
#pragma unroll
    for (int i = 0; i < GDIM; i += 4) {
      p0 = fmaf(cur[i + 0], wr[64 + i + 0], p0);
      p1 = fmaf(cur[i + 1], wr[64 + i + 1], p1);
      p2 = fmaf(cur[i + 2], wr[64 + i + 2], p2);
      p3 = fmaf(cur[i + 3], wr[64 + i + 3], p3);
    }
    float h = (p0 + p1) + (p2 + p3) + b1[o];
    h = fmaxf(h, 0.0f);
    z = fmaf(h, w2[o], z);
  }
  return 1.0f / (1.0f + __expf(-z));
}

__global__ __launch_bounds__(256, 2) void cascade_kernel(
    const int* __restrict__ ids0, const int* __restrict__ ids1,
    const int* __restrict__ ids2,
    const float* __restrict__ emb0, const float* __restrict__ emb1,
    const float* __restrict__ emb2,
    const float* __restrict__ w1t0, const float* __restrict__ b1_0,
    const float* __restrict__ w2_0, const float* __restrict__ b2_0,
    const float* __restrict__ w1t1, const float* __restrict__ b1_1,
    const float* __restrict__ w2_1, const float* __restrict__ b2_1,
    float* __restrict__ out, int n) {
  int idx = blockIdx.x * 256 + threadIdx.x;
  if (idx >= n) return;

  float cur[GDIM], fine[GDIM];

  // cur = emb2[ids2]
  {
    long b = (long)ids2[idx] << 6;
#pragma unroll
    for (int k = 0; k < 16; ++k)
      *(float4*)(cur + 4 * k) = *(const float4*)(emb2 + b + 4 * k);
  }
  // level 1: fine = emb1[ids1]; gate g1; blend
  {
    long b = (long)ids1[idx] << 6;
#pragma unroll
    for (int k = 0; k < 16; ++k)
      *(float4*)(fine + 4 * k) = *(const float4*)(emb1 + b + 4 * k);
    float g = gate_eval(fine, cur, w1t1, b1_1, w2_1, b2_1);
#pragma unroll
    for (int d = 0; d < GDIM; ++d)
      cur[d] = fmaf(g, fine[d] - cur[d], cur[d]);
  }
  // level 0: fine = emb0[ids0]; gate g0; blend
  {
    long b = (long)ids0[idx] << 6;
#pragma unroll
    for (int k = 0; k < 16; ++k)
      *(float4*)(fine + 4 * k) = *(const float4*)(emb0 + b + 4 * k);
    float g = gate_eval(fine, cur, w1t0, b1_0, w2_0, b2_0);
#pragma unroll
    for (int d = 0; d < GDIM; ++d)
      cur[d] = fmaf(g, fine[d] - cur[d], cur[d]);
  }
  // store
  {
    long b = (long)idx << 6;
#pragma unroll
    for (int k = 0; k < 16; ++k)
      *(float4*)(out + b + 4 * k) = *(const float4*)(cur + 4 * k);
  }
}

extern "C" void kernel_launch(void* const* d_in, const int* in_sizes, int n_in,
                              void* d_out, int out_size, void* d_ws,
                              size_t ws_size, hipStream_t stream) {
  const int* ids0 = (const int*)d_in[0];
  const int* ids1 = (const int*)d_in[1];
  const int* ids2 = (const int*)d_in[2];
  const float* emb0 = (const float*)d_in[3];
  const float* emb1 = (const float*)d_in[4];
  const float* emb2 = (const float*)d_in[5];
  const float* g0w1 = (const float*)d_in[6];
  const float* g0b1 = (const float*)d_in[7];
  const float* g0w2 = (const float*)d_in[8];
  const float* g0b2 = (const float*)d_in[9];
  const float* g1w1 = (const float*)d_in[10];
  const float* g1b1 = (const float*)d_in[11];
  const float* g1w2 = (const float*)d_in[12];
  const float* g1b2 = (const float*)d_in[13];
  float* out = (float*)d_out;
  float* wst = (float*)d_ws;  // [2][32][128] f32 = 32 KiB

  int n = in_sizes[0];  // B*H tokens

  hipLaunchKernelGGL(prep_transpose, dim3(32), dim3(256), 0, stream,
                     g0w1, g1w1, wst);

  int blocks = (n + 255) / 256;
  hipLaunchKernelGGL(cascade_kernel, dim3(blocks), dim3(256), 0, stream,
                     ids0, ids1, ids2, emb0, emb1, emb2,
                     wst, g0b1, g0w2, g0b2,          // gate 0 (transposed w1)
                     wst + 4096, g1b1, g1w2, g1b2,   // gate 1 (transposed w1)
                     out, n);
}

// Round 2
// 681.424 us; speedup vs baseline: 1.0286x; 1.0286x over previous
//
#include <hip/hip_runtime.h>

// CascadeHierarchicalEmbedding: 3-level gated embedding cascade.
// ids: [B,H] int32 x3; emb tables f32 [V,64]; two gate MLPs 128->32->1.
// out: f32 [B,H,64].  N = B*H = 819200 tokens.
//
// R2: LDS-staged version. Global loads/stores are wave-coalesced (16 lanes
// cover one 256-B row contiguously); gate compute stays thread-per-token with
// wave-uniform scalar weight loads (w1 pre-transposed into d_ws).

#define GDIM 64
#define TOK  128   // tokens per block
#define NTHR 128
#define STR4 17    // LDS row stride in float4 units (68 floats = 272 B, 16-B aligned, bank-rotated)

// Transpose the two gate w1 matrices [128,32] -> [32,128] into workspace so
// each output-neuron's weight row is contiguous (s_load-friendly wave-uniform
// access in the main kernel).
__global__ __launch_bounds__(256) void prep_transpose(
    const float* __restrict__ g0w1, const float* __restrict__ g1w1,
    float* __restrict__ wst) {
  int t = blockIdx.x * 256 + threadIdx.x;
  if (t < 4096) {
    int o = t >> 7, i = t & 127;
    wst[t] = g0w1[i * 32 + o];              // wst[0][o][i]
  } else if (t < 8192) {
    int u = t - 4096;
    int o = u >> 7, i = u & 127;
    wst[t] = g1w1[i * 32 + o];              // wst[1][o][i]
  }
}

// h = relu(x @ w1 + b1); g = sigmoid(h @ w2 + b2), x = concat(fine, cur).
// w1t transposed [32][128]; weight accesses wave-uniform -> scalar loads.
__device__ __forceinline__ float gate_eval(
    const float (&fine)[GDIM], const float (&cur)[GDIM],
    const float* __restrict__ w1t, const float* __restrict__ b1,
    const float* __restrict__ w2, const float* __restrict__ b2) {
  float z = b2[0];
  for (int o = 0; o < 32; ++o) {
    const float* __restrict__ wr = w1t + (o << 7);
    float p0 = 0.f, p1 = 0.f, p2 = 0.f, p3 = 0.f;
#pragma unroll
    for (int i = 0; i < GDIM; i += 4) {
      p0 = fmaf(fine[i + 0], wr[i + 0], p0);
      p1 = fmaf(fine[i + 1], wr[i + 1], p1);
      p2 = fmaf(fine[i + 2], wr[i + 2], p2);
      p3 = fmaf(fine[i + 3], wr[i + 3], p3);
    }
#pragma unroll
    for (int i = 0; i < GDIM; i += 4) {
      p0 = fmaf(cur[i + 0], wr[64 + i + 0], p0);
      p1 = fmaf(cur[i + 1], wr[64 + i + 1], p1);
      p2 = fmaf(cur[i + 2], wr[64 + i + 2], p2);
      p3 = fmaf(cur[i + 3], wr[64 + i + 3], p3);
    }
    float h = (p0 + p1) + (p2 + p3) + b1[o];
    h = fmaxf(h, 0.0f);
    z = fmaf(h, w2[o], z);
  }
  return 1.0f / (1.0f + __expf(-z));
}

__global__ __launch_bounds__(NTHR, 2) void cascade_kernel(
    const int* __restrict__ ids0, const int* __restrict__ ids1,
    const int* __restrict__ ids2,
    const float* __restrict__ emb0, const float* __restrict__ emb1,
    const float* __restrict__ emb2,
    const float* __restrict__ w1t0, const float* __restrict__ b1_0,
    const float* __restrict__ w2_0, const float* __restrict__ b2_0,
    const float* __restrict__ w1t1, const float* __restrict__ b1_1,
    const float* __restrict__ w2_1, const float* __restrict__ b2_1,
    float* __restrict__ out, int n) {
  __shared__ float4 buf[TOK * STR4];   // 34,816 B staging buffer
  __shared__ int lid[3][TOK];

  const int tid = threadIdx.x;
  const int base = blockIdx.x * TOK;

  // stage ids (coalesced)
  {
    int g = base + tid;
    int gc = g < n ? g : 0;
    lid[0][tid] = ids0[gc];
    lid[1][tid] = ids1[gc];
    lid[2][tid] = ids2[gc];
  }

  const int c = tid & 15;    // float4 chunk within a row (16 per row)
  const int r0 = tid >> 4;   // 0..7: row subgroup

  // Cooperative gather: 16 consecutive lanes load one 256-B row contiguously.
  auto fill = [&](const float* __restrict__ tab, const int* __restrict__ idr) {
#pragma unroll
    for (int s = 0; s < 16; ++s) {
      int row = s * 8 + r0;
      long rb = (long)idr[row] << 4;               // row base in float4 units
      buf[row * STR4 + c] = ((const float4*)tab)[rb + c];
    }
  };
  // Thread-per-token: pull own row from LDS into registers.
  auto readrow = [&](float* dst) {
#pragma unroll
    for (int k = 0; k < 16; ++k)
      *(float4*)(dst + 4 * k) = buf[tid * STR4 + k];
  };

  float cur[GDIM], fine[GDIM];

  __syncthreads();                 // ids visible
  fill(emb2, lid[2]);
  __syncthreads();
  readrow(cur);
  __syncthreads();                 // WAR: reads done before refill

  fill(emb1, lid[1]);
  __syncthreads();
  readrow(fine);
  {
    float g = gate_eval(fine, cur, w1t1, b1_1, w2_1, b2_1);
#pragma unroll
    for (int d = 0; d < GDIM; ++d)
      cur[d] = fmaf(g, fine[d] - cur[d], cur[d]);
  }
  __syncthreads();

  fill(emb0, lid[0]);
  __syncthreads();
  readrow(fine);
  {
    float g = gate_eval(fine, cur, w1t0, b1_0, w2_0, b2_0);
#pragma unroll
    for (int d = 0; d < GDIM; ++d)
      cur[d] = fmaf(g, fine[d] - cur[d], cur[d]);
  }
  __syncthreads();

  // stage result rows in LDS
#pragma unroll
  for (int k = 0; k < 16; ++k)
    buf[tid * STR4 + k] = *(float4*)(cur + 4 * k);
  __syncthreads();

  // fully-coalesced contiguous block store (32 KB per block)
#pragma unroll
  for (int s = 0; s < 16; ++s) {
    int row = s * 8 + r0;
    int g = base + row;
    if (g < n)
      ((float4*)out)[((long)g << 4) + c] = buf[row * STR4 + c];
  }
}

extern "C" void kernel_launch(void* const* d_in, const int* in_sizes, int n_in,
                              void* d_out, int out_size, void* d_ws,
                              size_t ws_size, hipStream_t stream) {
  const int* ids0 = (const int*)d_in[0];
  const int* ids1 = (const int*)d_in[1];
  const int* ids2 = (const int*)d_in[2];
  const float* emb0 = (const float*)d_in[3];
  const float* emb1 = (const float*)d_in[4];
  const float* emb2 = (const float*)d_in[5];
  const float* g0w1 = (const float*)d_in[6];
  const float* g0b1 = (const float*)d_in[7];
  const float* g0w2 = (const float*)d_in[8];
  const float* g0b2 = (const float*)d_in[9];
  const float* g1w1 = (const float*)d_in[10];
  const float* g1b1 = (const float*)d_in[11];
  const float* g1w2 = (const float*)d_in[12];
  const float* g1b2 = (const float*)d_in[13];
  float* out = (float*)d_out;
  float* wst = (float*)d_ws;  // [2][32][128] f32 = 32 KiB

  int n = in_sizes[0];  // B*H tokens

  hipLaunchKernelGGL(prep_transpose, dim3(32), dim3(256), 0, stream,
                     g0w1, g1w1, wst);

  int blocks = (n + TOK - 1) / TOK;
  hipLaunchKernelGGL(cascade_kernel, dim3(blocks), dim3(NTHR), 0, stream,
                     ids0, ids1, ids2, emb0, emb1, emb2,
                     wst, g0b1, g0w2, g0b2,          // gate 0 (transposed w1)
                     wst + 4096, g1b1, g1w2, g1b2,   // gate 1 (transposed w1)
                     out, n);
}

// Round 3
// 190.354 us; speedup vs baseline: 3.6820x; 3.5798x over previous
//
#include <hip/hip_runtime.h>

// CascadeHierarchicalEmbedding, R3: gate MLPs on MFMA (split-bf16, 3 passes).
// Per block: 128 tokens staged in LDS X[128][132] = [fine(64) | cur(64)] f32.
//   gather emb2->cur, emb1->fine; gate1 via mfma_f32_16x16x32_bf16; blend;
//   gather emb0->fine; gate0; blend; coalesced store of cur.
// W1 pre-packed into hi/lo bf16 fragments (d_ws, 32 KB) by prep kernel.

#define TOKB 128
#define XPITCH 132   // floats per X row (528 B, 16-B aligned, 8-way-max banks)

typedef float f32x4 __attribute__((ext_vector_type(4)));
typedef short v8s __attribute__((ext_vector_type(8)));

__device__ __forceinline__ unsigned short bf16_rne(float f) {
  union { float f; unsigned int u; } a; a.f = f;
  return (unsigned short)((a.u + 0x7FFFu + ((a.u >> 16) & 1u)) >> 16);
}
__device__ __forceinline__ float bf16_to_f32(unsigned short h) {
  union { unsigned int u; float f; } a; a.u = ((unsigned int)h) << 16;
  return a.f;
}

// Pack W1 (f32 [128][32]) into MFMA B-fragments, hi/lo bf16.
// frag id = gate*16 + pass*8 + kt*2 + nt ; element (lane, j):
//   k = kt*32 + (lane>>4)*8 + j, o = nt*16 + (lane&15)  -> w1[k][o]
__global__ __launch_bounds__(256) void prep_frags(
    const float* __restrict__ g0w1, const float* __restrict__ g1w1,
    unsigned short* __restrict__ wsf) {
  int t = blockIdx.x * 256 + threadIdx.x;   // 2048 threads
  if (t >= 2048) return;
  int lane = t & 63, fragid = t >> 6;       // 0..31
  int gate = fragid >> 4, p = (fragid >> 3) & 1;
  int kt = (fragid >> 1) & 3, nt = fragid & 1;
  const float* __restrict__ w1 = gate ? g1w1 : g0w1;
#pragma unroll
  for (int j = 0; j < 8; ++j) {
    int k = kt * 32 + ((lane >> 4) << 3) + j;
    int o = nt * 16 + (lane & 15);
    float f = w1[k * 32 + o];
    unsigned short hi = bf16_rne(f);
    unsigned short lo = bf16_rne(f - bf16_to_f32(hi));
    wsf[fragid * 512 + lane * 8 + j] = p ? lo : hi;
  }
}

// One gate level for this wave's 32 tokens (2 m-tiles of 16).
// X rows: [fine 0..63 | cur 64..127]; blend result written back to cur half.
__device__ __forceinline__ void gate_level(
    float* __restrict__ X, const uint4* __restrict__ wfragG,
    float b1o0, float b1o1, float w2o0, float w2o1, float b2s,
    int wave, int lane) {
  // preload all 16 W fragments for this gate (hi: 0..7, lo: 8..15)
  uint4 wf[16];
#pragma unroll
  for (int i = 0; i < 16; ++i) wf[i] = wfragG[i * 64 + lane];

#pragma unroll
  for (int mtl = 0; mtl < 2; ++mtl) {
    int mt = wave * 2 + mtl;
    int tokenA = mt * 16 + (lane & 15);
    f32x4 acc0 = {0.f, 0.f, 0.f, 0.f};
    f32x4 acc1 = {0.f, 0.f, 0.f, 0.f};
#pragma unroll
    for (int kt = 0; kt < 4; ++kt) {
      const float* xp = &X[tokenA * XPITCH + kt * 32 + ((lane >> 4) << 3)];
      float xv[8];
      *(float4*)(xv + 0) = *(const float4*)(xp + 0);
      *(float4*)(xv + 4) = *(const float4*)(xp + 4);
      v8s ahi, alo;
#pragma unroll
      for (int e = 0; e < 8; ++e) {
        unsigned short h = bf16_rne(xv[e]);
        unsigned short l = bf16_rne(xv[e] - bf16_to_f32(h));
        ahi[e] = (short)h;
        alo[e] = (short)l;
      }
      v8s whi0 = *(const v8s*)&wf[kt * 2 + 0];
      v8s whi1 = *(const v8s*)&wf[kt * 2 + 1];
      v8s wlo0 = *(const v8s*)&wf[8 + kt * 2 + 0];
      v8s wlo1 = *(const v8s*)&wf[8 + kt * 2 + 1];
      acc0 = __builtin_amdgcn_mfma_f32_16x16x32_bf16(ahi, whi0, acc0, 0, 0, 0);
      acc1 = __builtin_amdgcn_mfma_f32_16x16x32_bf16(ahi, whi1, acc1, 0, 0, 0);
      acc0 = __builtin_amdgcn_mfma_f32_16x16x32_bf16(alo, whi0, acc0, 0, 0, 0);
      acc1 = __builtin_amdgcn_mfma_f32_16x16x32_bf16(alo, whi1, acc1, 0, 0, 0);
      acc0 = __builtin_amdgcn_mfma_f32_16x16x32_bf16(ahi, wlo0, acc0, 0, 0, 0);
      acc1 = __builtin_amdgcn_mfma_f32_16x16x32_bf16(ahi, wlo1, acc1, 0, 0, 0);
    }
    // layer 2: per lane covers neuron o=lane&15 (+16); C row=(lane>>4)*4+j
    float z[4];
#pragma unroll
    for (int j = 0; j < 4; ++j)
      z[j] = fmaxf(acc0[j] + b1o0, 0.f) * w2o0 +
             fmaxf(acc1[j] + b1o1, 0.f) * w2o1;
    // butterfly over lane bits 0..3 (within 16-lane quarter groups)
#pragma unroll
    for (int m = 1; m <= 8; m <<= 1) {
#pragma unroll
      for (int j = 0; j < 4; ++j) z[j] += __shfl_xor(z[j], m);
    }
    // blend: quarter-group q owns tokens mt*16+q*4+j; lane handles chunk c4
    int c4 = lane & 15, q = lane >> 4;
#pragma unroll
    for (int j = 0; j < 4; ++j) {
      float g = 1.f / (1.f + __expf(-(z[j] + b2s)));
      int row = mt * 16 + q * 4 + j;
      float4 fv = *(float4*)&X[row * XPITCH + c4 * 4];
      float4 uv = *(float4*)&X[row * XPITCH + 64 + c4 * 4];
      float4 ov;
      ov.x = fmaf(g, fv.x - uv.x, uv.x);
      ov.y = fmaf(g, fv.y - uv.y, uv.y);
      ov.z = fmaf(g, fv.z - uv.z, uv.z);
      ov.w = fmaf(g, fv.w - uv.w, uv.w);
      *(float4*)&X[row * XPITCH + 64 + c4 * 4] = ov;
    }
  }
}

__global__ __launch_bounds__(256, 2) void cascade_mfma(
    const int* __restrict__ ids0, const int* __restrict__ ids1,
    const int* __restrict__ ids2,
    const float* __restrict__ emb0, const float* __restrict__ emb1,
    const float* __restrict__ emb2,
    const uint4* __restrict__ wfrag,
    const float* __restrict__ b1_0, const float* __restrict__ w2_0,
    const float* __restrict__ b2_0,
    const float* __restrict__ b1_1, const float* __restrict__ w2_1,
    const float* __restrict__ b2_1,
    float* __restrict__ out, int n) {
  __shared__ float X[TOKB * XPITCH];
  __shared__ int lid[3][TOKB];
  const int tid = threadIdx.x, lane = tid & 63, wave = tid >> 6;
  const int base = blockIdx.x * TOKB;

  if (tid < TOKB) {
    int g = base + tid;
    int gc = g < n ? g : 0;
    lid[0][tid] = ids0[gc];
    lid[1][tid] = ids1[gc];
    lid[2][tid] = ids2[gc];
  }

  const int c = tid & 15, r0 = tid >> 4;  // 16 lanes cover one 256-B row

  // per-gate layer-2 params (per-lane neuron o = lane&15)
  const int o = lane & 15;
  float b1o0_1 = b1_1[o], b1o1_1 = b1_1[o + 16];
  float w2o0_1 = w2_1[o], w2o1_1 = w2_1[o + 16];
  float b1o0_0 = b1_0[o], b1o1_0 = b1_0[o + 16];
  float w2o0_0 = w2_0[o], w2o1_0 = w2_0[o + 16];
  float b2s1 = b2_1[0], b2s0 = b2_0[0];

  __syncthreads();  // lid visible

  // gather: emb2 -> cur half, emb1 -> fine half (coalesced, 16 lanes/row)
#pragma unroll
  for (int s = 0; s < 8; ++s) {
    int row = s * 16 + r0;
    long rb = (long)lid[2][row] << 4;
    *(float4*)&X[row * XPITCH + 64 + c * 4] = ((const float4*)emb2)[rb + c];
  }
#pragma unroll
  for (int s = 0; s < 8; ++s) {
    int row = s * 16 + r0;
    long rb = (long)lid[1][row] << 4;
    *(float4*)&X[row * XPITCH + c * 4] = ((const float4*)emb1)[rb + c];
  }
  __syncthreads();

  // level 1 (gate index 1): frag base = gate1 -> +16 frags
  gate_level(X, wfrag + 16 * 64, b1o0_1, b1o1_1, w2o0_1, w2o1_1, b2s1, wave, lane);
  __syncthreads();

  // gather emb0 -> fine half
#pragma unroll
  for (int s = 0; s < 8; ++s) {
    int row = s * 16 + r0;
    long rb = (long)lid[0][row] << 4;
    *(float4*)&X[row * XPITCH + c * 4] = ((const float4*)emb0)[rb + c];
  }
  __syncthreads();

  // level 0 (gate index 0)
  gate_level(X, wfrag, b1o0_0, b1o1_0, w2o0_0, w2o1_0, b2s0, wave, lane);
  __syncthreads();

  // coalesced store of cur half
#pragma unroll
  for (int s = 0; s < 8; ++s) {
    int row = s * 16 + r0;
    int g = base + row;
    if (g < n)
      ((float4*)out)[(long)g * 16 + c] = *(float4*)&X[row * XPITCH + 64 + c * 4];
  }
}

extern "C" void kernel_launch(void* const* d_in, const int* in_sizes, int n_in,
                              void* d_out, int out_size, void* d_ws,
                              size_t ws_size, hipStream_t stream) {
  const int* ids0 = (const int*)d_in[0];
  const int* ids1 = (const int*)d_in[1];
  const int* ids2 = (const int*)d_in[2];
  const float* emb0 = (const float*)d_in[3];
  const float* emb1 = (const float*)d_in[4];
  const float* emb2 = (const float*)d_in[5];
  const float* g0w1 = (const float*)d_in[6];
  const float* g0b1 = (const float*)d_in[7];
  const float* g0w2 = (const float*)d_in[8];
  const float* g0b2 = (const float*)d_in[9];
  const float* g1w1 = (const float*)d_in[10];
  const float* g1b1 = (const float*)d_in[11];
  const float* g1w2 = (const float*)d_in[12];
  const float* g1b2 = (const float*)d_in[13];
  float* out = (float*)d_out;

  int n = in_sizes[0];  // B*H tokens

  // pack W1 fragments (32 KB) into workspace
  hipLaunchKernelGGL(prep_frags, dim3(8), dim3(256), 0, stream,
                     g0w1, g1w1, (unsigned short*)d_ws);

  int blocks = (n + TOKB - 1) / TOKB;
  hipLaunchKernelGGL(cascade_mfma, dim3(blocks), dim3(256), 0, stream,
                     ids0, ids1, ids2, emb0, emb1, emb2,
                     (const uint4*)d_ws,
                     g0b1, g0w2, g0b2,
                     g1b1, g1w2, g1b2,
                     out, n);
}

// Round 4
// 163.819 us; speedup vs baseline: 4.2785x; 1.1620x over previous
//
#include <hip/hip_runtime.h>

// CascadeHierarchicalEmbedding, R4.
// - gates on MFMA with swapped operands: D[neuron][token] so gate scalar lands
//   at col=token=lane&15 == A-side token index -> cur stays in frag registers.
// - LDS = two 16 KB fine-row buffers; all gathers via global_load_lds (16 B),
//   XOR-swizzled through pre-swizzled GLOBAL addresses (linear LDS dest).
// - emb0 gather issued before gate-1 compute (latency hidden under MFMA).
// - 3 barriers per block; 64 tokens/block, 256 threads (1 token-tile/wave).

#define TOKB 64
#define NTHR 256

typedef float f32x4 __attribute__((ext_vector_type(4)));
typedef short v8s __attribute__((ext_vector_type(8)));
typedef __attribute__((address_space(3))) uint32_t lds_u32_t;
typedef __attribute__((address_space(1))) const uint32_t glb_u32_t;

static __device__ __forceinline__ unsigned short bf16_rne(float f) {
  union { float f; unsigned int u; } a; a.f = f;
  return (unsigned short)((a.u + 0x7FFFu + ((a.u >> 16) & 1u)) >> 16);
}
static __device__ __forceinline__ float bf16_to_f32(unsigned short h) {
  union { unsigned int u; float f; } a; a.u = ((unsigned int)h) << 16;
  return a.f;
}

// Pack W1 (f32 [128][32]) into bf16 MFMA fragments (hi only).
// fragid = gate*8 + kt*2 + nt; elem (lane,j): k=kt*32+(lane>>4)*8+j,
// o=nt*16+(lane&15); fragment holds w1[k][o]  (A-operand = W1^T).
__global__ __launch_bounds__(256) void prep_frags(
    const float* __restrict__ g0w1, const float* __restrict__ g1w1,
    unsigned short* __restrict__ wsf) {
  int t = blockIdx.x * 256 + threadIdx.x;
  if (t >= 1024) return;
  int lane = t & 63, fragid = t >> 6;
  int gate = fragid >> 3, kt = (fragid >> 1) & 3, nt = fragid & 1;
  const float* __restrict__ w1 = gate ? g1w1 : g0w1;
#pragma unroll
  for (int j = 0; j < 8; ++j) {
    int k = kt * 32 + ((lane >> 4) << 3) + j;
    int o = nt * 16 + (lane & 15);
    wsf[fragid * 512 + lane * 8 + j] = bf16_rne(w1[k * 32 + o]);
  }
}

// One gate level: MFMA z = W1^T x (split-bf16 x), relu+layer2 per-lane,
// 2-shuffle reduce to z[token], sigmoid, blend cur (frag regs) with fine.
static __device__ __forceinline__ void gate_and_blend(
    const float4* __restrict__ Xf, const uint4* __restrict__ wfragG,
    const float* __restrict__ b1, const float* __restrict__ w2,
    const float* __restrict__ b2,
    float (&cur0)[8], float (&cur1)[8], int lane, int q, int t16, int myrow) {
  uint4 wf[8];
#pragma unroll
  for (int i = 0; i < 8; ++i) wf[i] = wfragG[i * 64 + lane];

  const f32x4 b1a = *(const f32x4*)&b1[q * 4];
  const f32x4 b1b = *(const f32x4*)&b1[16 + q * 4];
  const f32x4 w2a = *(const f32x4*)&w2[q * 4];
  const f32x4 w2b = *(const f32x4*)&w2[16 + q * 4];
  const float b2s = b2[0];

  // fine frags f32 from LDS (XOR-swizzled chunks; row&15 == t16)
  float fine0[8], fine1[8];
  {
    const float4 f0 = Xf[myrow * 16 + ((q * 2 + 0) ^ t16)];
    const float4 f1 = Xf[myrow * 16 + ((q * 2 + 1) ^ t16)];
    const float4 f2 = Xf[myrow * 16 + ((8 + q * 2 + 0) ^ t16)];
    const float4 f3 = Xf[myrow * 16 + ((8 + q * 2 + 1) ^ t16)];
    fine0[0] = f0.x; fine0[1] = f0.y; fine0[2] = f0.z; fine0[3] = f0.w;
    fine0[4] = f1.x; fine0[5] = f1.y; fine0[6] = f1.z; fine0[7] = f1.w;
    fine1[0] = f2.x; fine1[1] = f2.y; fine1[2] = f2.z; fine1[3] = f2.w;
    fine1[4] = f3.x; fine1[5] = f3.y; fine1[6] = f3.z; fine1[7] = f3.w;
  }

  f32x4 acc0 = {0.f, 0.f, 0.f, 0.f};
  f32x4 acc1 = {0.f, 0.f, 0.f, 0.f};
#pragma unroll
  for (int ktp = 0; ktp < 4; ++ktp) {
    const float* xs = (ktp == 0) ? fine0 : (ktp == 1) ? fine1
                    : (ktp == 2) ? cur0 : cur1;
    v8s xhi, xlo;
#pragma unroll
    for (int e = 0; e < 8; ++e) {
      unsigned short h = bf16_rne(xs[e]);
      xhi[e] = (short)h;
      xlo[e] = (short)bf16_rne(xs[e] - bf16_to_f32(h));
    }
    v8s w0 = *(const v8s*)&wf[ktp * 2 + 0];
    v8s w1v = *(const v8s*)&wf[ktp * 2 + 1];
    acc0 = __builtin_amdgcn_mfma_f32_16x16x32_bf16(w0, xhi, acc0, 0, 0, 0);
    acc1 = __builtin_amdgcn_mfma_f32_16x16x32_bf16(w1v, xhi, acc1, 0, 0, 0);
    acc0 = __builtin_amdgcn_mfma_f32_16x16x32_bf16(w0, xlo, acc0, 0, 0, 0);
    acc1 = __builtin_amdgcn_mfma_f32_16x16x32_bf16(w1v, xlo, acc1, 0, 0, 0);
  }

  // layer 2: lane covers neurons q*4+j (acc0) and 16+q*4+j (acc1)
  float zp = 0.f;
#pragma unroll
  for (int j = 0; j < 4; ++j) {
    zp += fmaxf(acc0[j] + b1a[j], 0.f) * w2a[j]
        + fmaxf(acc1[j] + b1b[j], 0.f) * w2b[j];
  }
  zp += __shfl_xor(zp, 16);
  zp += __shfl_xor(zp, 32);
  float g = 1.f / (1.f + __expf(-(zp + b2s)));
#pragma unroll
  for (int e = 0; e < 8; ++e) {
    cur0[e] = fmaf(g, fine0[e] - cur0[e], cur0[e]);
    cur1[e] = fmaf(g, fine1[e] - cur1[e], cur1[e]);
  }
}

__global__ __launch_bounds__(NTHR, 4) void cascade_mfma(
    const int* __restrict__ ids0, const int* __restrict__ ids1,
    const int* __restrict__ ids2,
    const float* __restrict__ emb0, const float* __restrict__ emb1,
    const float* __restrict__ emb2,
    const uint4* __restrict__ wfrag,
    const float* __restrict__ b1_0, const float* __restrict__ w2_0,
    const float* __restrict__ b2_0,
    const float* __restrict__ b1_1, const float* __restrict__ w2_1,
    const float* __restrict__ b2_1,
    float* __restrict__ out, int n) {
  __shared__ float4 XA[TOKB * 16];   // 16 KB
  __shared__ float4 XB[TOKB * 16];   // 16 KB
  const int tid = threadIdx.x, lane = tid & 63, wave = tid >> 6;
  const long base = (long)blockIdx.x * TOKB;

  // gather mapping: wave handles 4 consecutive rows per issue; lane>>4 = row
  // in group, lane&15 = chunk. Global source pre-swizzled by chunk^(row&15)
  // so the LINEAR gload_lds dest yields the swizzled LDS layout.
  const int rsub = lane >> 4;
  const int c = lane & 15;
  const int rb4 = wave * 4 + rsub;          // == row & 15 for all s
  const int swb = ((c ^ rb4) << 4);         // swizzled byte offset in row

  const int q = lane >> 4;
  const int t16 = lane & 15;
  const int myrow = wave * 16 + t16;        // this thread's token row (tile=wave)

  // ---- phase 1: issue emb2 -> XA and emb1 -> XB (direct-to-LDS, async)
#pragma unroll
  for (int s = 0; s < 4; ++s) {
    int row = s * 16 + rb4;
    long gi = base + row; if (gi >= n) gi = 0;
    long i2 = ids2[gi];
    long i1 = ids1[gi];
    const char* g2 = (const char*)emb2 + (i2 << 8) + swb;
    const char* g1 = (const char*)emb1 + (i1 << 8) + swb;
    __builtin_amdgcn_global_load_lds(
        (glb_u32_t*)g2, (lds_u32_t*)(uint32_t*)&XA[(s * 16 + wave * 4) * 16],
        16, 0, 0);
    __builtin_amdgcn_global_load_lds(
        (glb_u32_t*)g1, (lds_u32_t*)(uint32_t*)&XB[(s * 16 + wave * 4) * 16],
        16, 0, 0);
  }
  __syncthreads();   // barrier drains vmcnt: XA (emb2) and XB (emb1) ready

  // ---- cur = emb2 row, read into frag registers (f32)
  float cur0[8], cur1[8];
  {
    const float4 a0 = XA[myrow * 16 + ((q * 2 + 0) ^ t16)];
    const float4 a1 = XA[myrow * 16 + ((q * 2 + 1) ^ t16)];
    const float4 a2 = XA[myrow * 16 + ((8 + q * 2 + 0) ^ t16)];
    const float4 a3 = XA[myrow * 16 + ((8 + q * 2 + 1) ^ t16)];
    cur0[0] = a0.x; cur0[1] = a0.y; cur0[2] = a0.z; cur0[3] = a0.w;
    cur0[4] = a1.x; cur0[5] = a1.y; cur0[6] = a1.z; cur0[7] = a1.w;
    cur1[0] = a2.x; cur1[1] = a2.y; cur1[2] = a2.z; cur1[3] = a2.w;
    cur1[4] = a3.x; cur1[5] = a3.y; cur1[6] = a3.z; cur1[7] = a3.w;
  }
  __syncthreads();   // all waves done reading XA (WAR vs emb0 refill)

  // ---- issue emb0 -> XA now; latency hides under gate-1 compute
#pragma unroll
  for (int s = 0; s < 4; ++s) {
    int row = s * 16 + rb4;
    long gi = base + row; if (gi >= n) gi = 0;
    long i0 = ids0[gi];
    const char* g0 = (const char*)emb0 + (i0 << 8) + swb;
    __builtin_amdgcn_global_load_lds(
        (glb_u32_t*)g0, (lds_u32_t*)(uint32_t*)&XA[(s * 16 + wave * 4) * 16],
        16, 0, 0);
  }

  // ---- gate level 1 (fine = XB = emb1)
  gate_and_blend(XB, wfrag + 8 * 64, b1_1, w2_1, b2_1,
                 cur0, cur1, lane, q, t16, myrow);
  __syncthreads();   // drains vmcnt -> emb0 landed in XA

  // ---- gate level 0 (fine = XA = emb0)
  gate_and_blend(XA, wfrag, b1_0, w2_0, b2_0,
                 cur0, cur1, lane, q, t16, myrow);

  // ---- store: thread holds token myrow, dims q*8..+7 and 32+q*8..+7
  long gtok = base + myrow;
  if (gtok < n) {
    float4* op = (float4*)out + (gtok << 4);
    float4 o0 = {cur0[0], cur0[1], cur0[2], cur0[3]};
    float4 o1 = {cur0[4], cur0[5], cur0[6], cur0[7]};
    float4 o2 = {cur1[0], cur1[1], cur1[2], cur1[3]};
    float4 o3 = {cur1[4], cur1[5], cur1[6], cur1[7]};
    op[q * 2 + 0] = o0;
    op[q * 2 + 1] = o1;
    op[8 + q * 2 + 0] = o2;
    op[8 + q * 2 + 1] = o3;
  }
}

extern "C" void kernel_launch(void* const* d_in, const int* in_sizes, int n_in,
                              void* d_out, int out_size, void* d_ws,
                              size_t ws_size, hipStream_t stream) {
  const int* ids0 = (const int*)d_in[0];
  const int* ids1 = (const int*)d_in[1];
  const int* ids2 = (const int*)d_in[2];
  const float* emb0 = (const float*)d_in[3];
  const float* emb1 = (const float*)d_in[4];
  const float* emb2 = (const float*)d_in[5];
  const float* g0w1 = (const float*)d_in[6];
  const float* g0b1 = (const float*)d_in[7];
  const float* g0w2 = (const float*)d_in[8];
  const float* g0b2 = (const float*)d_in[9];
  const float* g1w1 = (const float*)d_in[10];
  const float* g1b1 = (const float*)d_in[11];
  const float* g1w2 = (const float*)d_in[12];
  const float* g1b2 = (const float*)d_in[13];
  float* out = (float*)d_out;

  int n = in_sizes[0];  // B*H tokens

  // pack W1 fragments (16 KB) into workspace
  hipLaunchKernelGGL(prep_frags, dim3(4), dim3(256), 0, stream,
                     g0w1, g1w1, (unsigned short*)d_ws);

  int blocks = (n + TOKB - 1) / TOKB;
  hipLaunchKernelGGL(cascade_mfma, dim3(blocks), dim3(NTHR), 0, stream,
                     ids0, ids1, ids2, emb0, emb1, emb2,
                     (const uint4*)d_ws,
                     g0b1, g0w2, g0b2,
                     g1b1, g1w2, g1b2,
                     out, n);
}

// Round 5
// 139.537 us; speedup vs baseline: 5.0230x; 1.1740x over previous
//
#include <hip/hip_runtime.h>

// CascadeHierarchicalEmbedding, R5: barrier-free persistent per-wave pipeline.
// Each wave owns 16-token tiles via grid-stride; 3 private 4KB LDS buffers
// (emb2/emb1/emb0). Per iteration: [vmcnt(4) -> tile t ready] [ds_read frags
// to regs; lgkmcnt(0)] [issue 12 gathers for t+1 + ids for t+2] [2 gates on
// MFMA] [store]. Next-tile HBM latency hides under current-tile compute.
// No __syncthreads anywhere. Gates: bf16-hi single-pass MFMA, b1 folded into
// accumulator init.

#define WPB 4      // waves per block (256 threads)
#define NBLK 1024  // persistent-ish grid

typedef float f32x4 __attribute__((ext_vector_type(4)));
typedef short v8s __attribute__((ext_vector_type(8)));
typedef __attribute__((address_space(3))) uint32_t lds_u32_t;
typedef __attribute__((address_space(1))) const uint32_t glb_u32_t;

static __device__ __forceinline__ unsigned short bf16_rne(float f) {
  union { float f; unsigned int u; } a; a.f = f;
  return (unsigned short)((a.u + 0x7FFFu + ((a.u >> 16) & 1u)) >> 16);
}

// Pack W1 (f32 [128][32]) into bf16 A-fragments (W1^T), gate0: frags 0..7,
// gate1: frags 8..15. fragid = gate*8 + kt*2 + nt; elem (lane,j):
// k = kt*32 + (lane>>4)*8 + j, o = nt*16 + (lane&15) -> w1[k][o].
__global__ __launch_bounds__(256) void prep_frags(
    const float* __restrict__ g0w1, const float* __restrict__ g1w1,
    unsigned short* __restrict__ wsf) {
  int t = blockIdx.x * 256 + threadIdx.x;
  if (t >= 1024) return;
  int lane = t & 63, fragid = t >> 6;
  int gate = fragid >> 3, kt = (fragid >> 1) & 3, nt = fragid & 1;
  const float* __restrict__ w1 = gate ? g1w1 : g0w1;
#pragma unroll
  for (int j = 0; j < 8; ++j) {
    int k = kt * 32 + ((lane >> 4) << 3) + j;
    int o = nt * 16 + (lane & 15);
    wsf[fragid * 512 + lane * 8 + j] = bf16_rne(w1[k * 32 + o]);
  }
}

// One gate level: z = W1^T x (bf16-hi), relu+layer2 per lane, 2-shuffle
// reduce, sigmoid, blend cur in place. b1 folded into acc init.
static __device__ __forceinline__ void gate_apply(
    const float (&fine)[16], float (&cur)[16], const uint4 (&wf)[8],
    f32x4 b1a, f32x4 b1b, f32x4 w2a, f32x4 w2b, float b2s) {
  v8s xf0, xf1, xc0, xc1;
#pragma unroll
  for (int e = 0; e < 8; ++e) {
    xf0[e] = (short)bf16_rne(fine[e]);
    xf1[e] = (short)bf16_rne(fine[8 + e]);
    xc0[e] = (short)bf16_rne(cur[e]);
    xc1[e] = (short)bf16_rne(cur[8 + e]);
  }
  f32x4 acc0 = b1a, acc1 = b1b;
  acc0 = __builtin_amdgcn_mfma_f32_16x16x32_bf16(*(const v8s*)&wf[0], xf0, acc0, 0, 0, 0);
  acc1 = __builtin_amdgcn_mfma_f32_16x16x32_bf16(*(const v8s*)&wf[1], xf0, acc1, 0, 0, 0);
  acc0 = __builtin_amdgcn_mfma_f32_16x16x32_bf16(*(const v8s*)&wf[2], xf1, acc0, 0, 0, 0);
  acc1 = __builtin_amdgcn_mfma_f32_16x16x32_bf16(*(const v8s*)&wf[3], xf1, acc1, 0, 0, 0);
  acc0 = __builtin_amdgcn_mfma_f32_16x16x32_bf16(*(const v8s*)&wf[4], xc0, acc0, 0, 0, 0);
  acc1 = __builtin_amdgcn_mfma_f32_16x16x32_bf16(*(const v8s*)&wf[5], xc0, acc1, 0, 0, 0);
  acc0 = __builtin_amdgcn_mfma_f32_16x16x32_bf16(*(const v8s*)&wf[6], xc1, acc0, 0, 0, 0);
  acc1 = __builtin_amdgcn_mfma_f32_16x16x32_bf16(*(const v8s*)&wf[7], xc1, acc1, 0, 0, 0);
  float zp = 0.f;
#pragma unroll
  for (int j = 0; j < 4; ++j)
    zp += fmaxf(acc0[j], 0.f) * w2a[j] + fmaxf(acc1[j], 0.f) * w2b[j];
  zp += __shfl_xor(zp, 16);
  zp += __shfl_xor(zp, 32);
  float g = 1.f / (1.f + __expf(-(zp + b2s)));
#pragma unroll
  for (int e = 0; e < 16; ++e) cur[e] = fmaf(g, fine[e] - cur[e], cur[e]);
}

__global__ __launch_bounds__(256) void cascade_pipe(
    const int* __restrict__ ids0, const int* __restrict__ ids1,
    const int* __restrict__ ids2,
    const float* __restrict__ emb0, const float* __restrict__ emb1,
    const float* __restrict__ emb2,
    const uint4* __restrict__ wfrag,
    const float* __restrict__ b1_0, const float* __restrict__ w2_0,
    const float* __restrict__ b2_0,
    const float* __restrict__ b1_1, const float* __restrict__ w2_1,
    const float* __restrict__ b2_1,
    float* __restrict__ out, int n) {
  __shared__ float4 F[WPB][3][256];  // per wave: emb2 | emb1 | emb0, 4KB each
  const int tid = threadIdx.x, lane = tid & 63, wave = tid >> 6;
  const int q = lane >> 4, t16 = lane & 15;
  const int ntiles = n >> 4;  // n divisible by 16
  const int nw = NBLK * WPB;
  int tile = blockIdx.x * WPB + wave;
  if (tile >= ntiles) return;
  float4* myF = &F[wave][0][0];

  // loop-invariant preloads: weight fragments + layer-2 params
  uint4 wfA[8], wfB[8];
#pragma unroll
  for (int i = 0; i < 8; ++i) {
    wfA[i] = wfrag[i * 64 + lane];        // gate0
    wfB[i] = wfrag[(8 + i) * 64 + lane];  // gate1
  }
  const f32x4 b1a0 = *(const f32x4*)&b1_0[q * 4], b1b0 = *(const f32x4*)&b1_0[16 + q * 4];
  const f32x4 w2a0 = *(const f32x4*)&w2_0[q * 4], w2b0 = *(const f32x4*)&w2_0[16 + q * 4];
  const f32x4 b1a1 = *(const f32x4*)&b1_1[q * 4], b1b1 = *(const f32x4*)&b1_1[16 + q * 4];
  const f32x4 w2a1 = *(const f32x4*)&w2_1[q * 4], w2b1 = *(const f32x4*)&w2_1[16 + q * 4];
  const float b2s0 = b2_0[0], b2s1 = b2_1[0];
  asm volatile("s_waitcnt vmcnt(0) lgkmcnt(0)" ::: "memory");  // drain preloads once

  // per-lane gather ids: table x, rows s*4+q of the tile
  int j0[4], j1[4], j2[4];
  auto loadids = [&](int t) {
    int tb = (t << 4) + q;
#pragma unroll
    for (int s = 0; s < 4; ++s) {
      j0[s] = ids0[tb + s * 4];
      j1[s] = ids1[tb + s * 4];
      j2[s] = ids2[tb + s * 4];
    }
  };
  // 12 direct-to-LDS gathers, XOR-swizzled via pre-swizzled global source
  auto issue12 = [&]() {
#pragma unroll
    for (int s = 0; s < 4; ++s) {
      int swb = ((t16 ^ (s * 4 + q)) << 4);
      __builtin_amdgcn_global_load_lds(
          (glb_u32_t*)((const char*)emb2 + (((long)j2[s]) << 8) + swb),
          (lds_u32_t*)(uint32_t*)(myF + 0 * 256 + s * 64), 16, 0, 0);
      __builtin_amdgcn_global_load_lds(
          (glb_u32_t*)((const char*)emb1 + (((long)j1[s]) << 8) + swb),
          (lds_u32_t*)(uint32_t*)(myF + 1 * 256 + s * 64), 16, 0, 0);
      __builtin_amdgcn_global_load_lds(
          (glb_u32_t*)((const char*)emb0 + (((long)j0[s]) << 8) + swb),
          (lds_u32_t*)(uint32_t*)(myF + 2 * 256 + s * 64), 16, 0, 0);
    }
  };

  // prologue: gathers(tile0) in flight, j = ids(tile0+nw)
  loadids(tile);
  issue12();  // compiler inserts the wait for j values before address use
  { int t2 = tile + nw; if (t2 >= ntiles) t2 = 0; loadids(t2); }

  for (; tile < ntiles; tile += nw) {
    // outstanding (in-order): gathers(t):12, ids:12, stores(prev):4
    // vmcnt(4) => gathers done, stores not waited on
    asm volatile("s_waitcnt vmcnt(4)" ::: "memory");
    __builtin_amdgcn_sched_barrier(0);

    // pull this tile's fragments to registers (swizzled chunks of row t16)
    float curv[16], f1v[16], f0v[16];
#pragma unroll
    for (int e = 0; e < 4; ++e) {
      int ci = (2 * q + (e & 1) + 8 * (e >> 1)) ^ t16;
      *(float4*)&curv[e * 4] = myF[0 * 256 + t16 * 16 + ci];
      *(float4*)&f1v[e * 4]  = myF[1 * 256 + t16 * 16 + ci];
      *(float4*)&f0v[e * 4]  = myF[2 * 256 + t16 * 16 + ci];
    }
    asm volatile("s_waitcnt lgkmcnt(0)" ::: "memory");  // reads done before refill
    __builtin_amdgcn_sched_barrier(0);

    issue12();  // gathers for tile+nw (hide under compute below)
    { int t2 = tile + 2 * nw; if (t2 >= ntiles) t2 = 0; loadids(t2); }

    // gate level 1 (fine = emb1), then level 0 (fine = emb0)
    gate_apply(f1v, curv, wfB, b1a1, b1b1, w2a1, w2b1, b2s1);
    gate_apply(f0v, curv, wfA, b1a0, b1b0, w2a0, w2b0, b2s0);

    // store token (tile*16 + t16): 4 x 16B, consecutive rows per 16-lane group
    long tok = ((long)tile << 4) + t16;
    float4* op = (float4*)out + (tok << 4);
    op[2 * q + 0]     = float4{curv[0], curv[1], curv[2], curv[3]};
    op[2 * q + 1]     = float4{curv[4], curv[5], curv[6], curv[7]};
    op[8 + 2 * q + 0] = float4{curv[8], curv[9], curv[10], curv[11]};
    op[8 + 2 * q + 1] = float4{curv[12], curv[13], curv[14], curv[15]};
  }
}

extern "C" void kernel_launch(void* const* d_in, const int* in_sizes, int n_in,
                              void* d_out, int out_size, void* d_ws,
                              size_t ws_size, hipStream_t stream) {
  const int* ids0 = (const int*)d_in[0];
  const int* ids1 = (const int*)d_in[1];
  const int* ids2 = (const int*)d_in[2];
  const float* emb0 = (const float*)d_in[3];
  const float* emb1 = (const float*)d_in[4];
  const float* emb2 = (const float*)d_in[5];
  const float* g0w1 = (const float*)d_in[6];
  const float* g0b1 = (const float*)d_in[7];
  const float* g0w2 = (const float*)d_in[8];
  const float* g0b2 = (const float*)d_in[9];
  const float* g1w1 = (const float*)d_in[10];
  const float* g1b1 = (const float*)d_in[11];
  const float* g1w2 = (const float*)d_in[12];
  const float* g1b2 = (const float*)d_in[13];
  float* out = (float*)d_out;

  int n = in_sizes[0];  // B*H tokens

  hipLaunchKernelGGL(prep_frags, dim3(4), dim3(256), 0, stream,
                     g0w1, g1w1, (unsigned short*)d_ws);

  hipLaunchKernelGGL(cascade_pipe, dim3(NBLK), dim3(256), 0, stream,
                     ids0, ids1, ids2, emb0, emb1, emb2,
                     (const uint4*)d_ws,
                     g0b1, g0w2, g0b2,
                     g1b1, g1w2, g1b2,
                     out, n);
}